// Round 1
// baseline (18009.138 us; speedup 1.0000x reference)
//
#include <hip/hip_runtime.h>
#include <cstddef>

#define NLEV 5
#define CCH 256
#define GRP 32
#define TH 4
#define TW 16
#define ICC 8
#define OCT 64
#define TOTROW 21330

static const int Hs[NLEV]   = {100, 50, 25, 13, 7};
static const int Ws[NLEV]   = {160, 80, 40, 20, 10};
static const int ROFF[NLEV] = {0, 16000, 20000, 21000, 21260};
static const int STRD[NLEV] = {8, 16, 32, 64, 128};

// ---------------------------------------------------------------------------
// Tower conv: y = conv3x3(x, w) + b, for both towers (blockIdx.z -> tower,n).
// Tile: 64 oc x (4 x 16) spatial. Thread: 2 oc x 8 consecutive x.
// ---------------------------------------------------------------------------
__global__ __launch_bounds__(256) void conv_tower(
    const float* __restrict__ inC, const float* __restrict__ inR,
    float* __restrict__ outC, float* __restrict__ outR,
    const float* __restrict__ wC, const float* __restrict__ bC,
    const float* __restrict__ wR, const float* __restrict__ bR,
    int H, int W)
{
    const int tower = blockIdx.z >> 1;
    const int n     = blockIdx.z & 1;
    const float* in  = tower ? inR : inC;
    float*       out = tower ? outR : outC;
    const float* wp  = tower ? wR : wC;
    const float* bp  = tower ? bR : bC;

    const int HW = H * W;
    const int tilesX = (W + TW - 1) / TW;
    const int tx0 = (blockIdx.x % tilesX) * TW;
    const int ty0 = (blockIdx.x / tilesX) * TH;
    const int oc0 = blockIdx.y * OCT;

    __shared__ float sIn[ICC][TH + 2][TW + 2];   // 8*6*18 = 864 floats
    __shared__ float sW[OCT][ICC * 9 + 1];       // 64*73 (pad kills bank stride)

    const int tid   = threadIdx.x;
    const int oc2   = tid >> 3;          // 0..31 -> 2 ocs each
    const int sp8   = tid & 7;           // 0..7  -> 8 positions each
    const int my_oc = oc0 + oc2 * 2;
    const int prow  = sp8 >> 1;          // 0..3
    const int pcol0 = (sp8 & 1) * 8;     // 0 or 8

    float acc0[8], acc1[8];
    const float b0 = bp[my_oc], b1 = bp[my_oc + 1];
#pragma unroll
    for (int j = 0; j < 8; ++j) { acc0[j] = b0; acc1[j] = b1; }

    const float* inN = in + (size_t)n * CCH * HW;

    for (int ic0 = 0; ic0 < CCH; ic0 += ICC) {
        __syncthreads();
        // stage input tile (zero-padded SAME borders)
        for (int e = tid; e < ICC * (TH + 2) * (TW + 2); e += 256) {
            int ic = e / 108;
            int r  = e % 108;
            int ly = r / 18;
            int lx = r % 18;
            int gy = ty0 + ly - 1;
            int gx = tx0 + lx - 1;
            float v = 0.f;
            if (gy >= 0 && gy < H && gx >= 0 && gx < W)
                v = inN[(size_t)(ic0 + ic) * HW + (size_t)gy * W + gx];
            sIn[ic][ly][lx] = v;
        }
        // stage weights: [oc][ic*9+tap], global layout [O][I][3][3]
        const float* wbase = wp + ((size_t)oc0 * CCH + ic0) * 9;
        for (int e = tid; e < OCT * ICC * 9; e += 256) {
            int o = e / 72;
            int r = e % 72;
            sW[o][r] = wbase[(size_t)o * CCH * 9 + r];
        }
        __syncthreads();

        for (int ic = 0; ic < ICC; ++ic) {
#pragma unroll
            for (int ky = 0; ky < 3; ++ky) {
                float row[10];
#pragma unroll
                for (int j = 0; j < 10; ++j) row[j] = sIn[ic][prow + ky][pcol0 + j];
                const float* w0 = &sW[oc2 * 2][ic * 9 + ky * 3];
                const float* w1 = &sW[oc2 * 2 + 1][ic * 9 + ky * 3];
#pragma unroll
                for (int kx = 0; kx < 3; ++kx) {
                    float a = w0[kx], c = w1[kx];
#pragma unroll
                    for (int j = 0; j < 8; ++j) {
                        acc0[j] += a * row[j + kx];
                        acc1[j] += c * row[j + kx];
                    }
                }
            }
        }
    }

    const int gy = ty0 + prow;
    if (gy < H) {
        float* o0 = out + (size_t)n * CCH * HW + (size_t)my_oc * HW + (size_t)gy * W;
#pragma unroll
        for (int j = 0; j < 8; ++j) {
            int gx = tx0 + pcol0 + j;
            if (gx < W) {
                o0[gx]      = acc0[j];
                o0[HW + gx] = acc1[j];
            }
        }
    }
}

// ---------------------------------------------------------------------------
// GroupNorm stats: one block per (group, n, tower); writes mean, rstd.
// ---------------------------------------------------------------------------
__global__ __launch_bounds__(256) void gn_stats(
    const float* __restrict__ yC, const float* __restrict__ yR,
    float* __restrict__ stats, int HW)
{
    const int g = blockIdx.x;      // 0..31
    const int n = blockIdx.y;      // 0..1
    const int tower = blockIdx.z;  // 0..1
    const float* y = (tower ? yR : yC) + (size_t)n * CCH * HW + (size_t)g * 8 * HW;
    const int tot = 8 * HW;
    float s = 0.f, ss = 0.f;
    for (int i = threadIdx.x; i < tot; i += 256) {
        float v = y[i];
        s += v; ss += v * v;
    }
#pragma unroll
    for (int off = 32; off; off >>= 1) {
        s  += __shfl_down(s, off);
        ss += __shfl_down(ss, off);
    }
    __shared__ float ls[4], lss[4];
    const int wid = threadIdx.x >> 6;
    if ((threadIdx.x & 63) == 0) { ls[wid] = s; lss[wid] = ss; }
    __syncthreads();
    if (threadIdx.x == 0) {
        s  = ls[0] + ls[1] + ls[2] + ls[3];
        ss = lss[0] + lss[1] + lss[2] + lss[3];
        float inv = 1.f / (float)tot;
        float m = s * inv;
        float var = ss * inv - m * m;
        float rstd = rsqrtf(var + 1e-5f);
        int idx = ((tower * 2 + n) * GRP + g) * 2;
        stats[idx] = m;
        stats[idx + 1] = rstd;
    }
}

// ---------------------------------------------------------------------------
// GroupNorm apply + ReLU: x = relu((y-m)*rstd*gw + gb)
// grid: (ceil(HW/256), n*256+c, tower)
// ---------------------------------------------------------------------------
__global__ __launch_bounds__(256) void gn_apply(
    const float* __restrict__ yC, const float* __restrict__ yR,
    float* __restrict__ xC, float* __restrict__ xR,
    const float* __restrict__ stats,
    const float* __restrict__ gwC, const float* __restrict__ gbC,
    const float* __restrict__ gwR, const float* __restrict__ gbR,
    int HW)
{
    const int tower = blockIdx.z;
    const int nc = blockIdx.y;
    const int n = nc >> 8;
    const int c = nc & 255;
    const int i = blockIdx.x * 256 + threadIdx.x;
    if (i >= HW) return;
    const float* y = tower ? yR : yC;
    float*       x = tower ? xR : xC;
    const float* gw = tower ? gwR : gwC;
    const float* gb = tower ? gbR : gbC;
    const int g = c >> 3;
    const int si = ((tower * 2 + n) * GRP + g) * 2;
    const float m = stats[si], rs = stats[si + 1];
    const size_t idx = ((size_t)(n * CCH + c)) * HW + i;
    float v = (y[idx] - m) * rs * gw[c] + gb[c];
    x[idx] = fmaxf(v, 0.f);
}

// ---------------------------------------------------------------------------
// Head: 85 channels (80 score from cls-tower, 1 ctr + 4 pred from box-tower),
// padded to 88. Epilogue (sigmoid*sigmoid, shift +/- reg boxes) fused; writes
// the final [n][row][84] output directly.
// ---------------------------------------------------------------------------
__global__ __launch_bounds__(256) void head_kernel(
    const float* __restrict__ xC, const float* __restrict__ xR,
    const float* __restrict__ sw, const float* __restrict__ sb,
    const float* __restrict__ cw, const float* __restrict__ cb,
    const float* __restrict__ pw, const float* __restrict__ pb,
    const float* __restrict__ scales, int lvl,
    float* __restrict__ out, int H, int W, int row_off, float stride)
{
    const int n = blockIdx.y;
    const int tilesX = (W + TW - 1) / TW;
    const int tx0 = (blockIdx.x % tilesX) * TW;
    const int ty0 = (blockIdx.x / tilesX) * TH;
    const int HW = H * W;
    const int tid  = threadIdx.x;
    const int pos  = tid & 63;
    const int q    = tid >> 6;
    const int base = q * 22;
    const int prow = pos >> 4;
    const int pcol = pos & 15;

    __shared__ float sInC[ICC][TH + 2][TW + 2];
    __shared__ float sInR[ICC][TH + 2][TW + 2];
    __shared__ float sWt[88][ICC * 9 + 1];       // reused as sOut after compute
    float (*sOut)[65] = reinterpret_cast<float (*)[65]>(&sWt[0][0]);

    float acc[22];
#pragma unroll
    for (int k = 0; k < 22; ++k) {
        int oc = base + k;
        float b = 0.f;
        if (oc < 80)       b = sb[oc];
        else if (oc == 80) b = cb[0];
        else if (oc < 85)  b = pb[oc - 81];
        acc[k] = b;
    }

    const float* xCn = xC + (size_t)n * CCH * HW;
    const float* xRn = xR + (size_t)n * CCH * HW;

    for (int ic0 = 0; ic0 < CCH; ic0 += ICC) {
        __syncthreads();
        for (int e = tid; e < 2 * 864; e += 256) {
            int which = (e >= 864);
            int e2 = which ? e - 864 : e;
            int ic = e2 / 108;
            int r  = e2 % 108;
            int ly = r / 18;
            int lx = r % 18;
            int gy = ty0 + ly - 1;
            int gx = tx0 + lx - 1;
            float v = 0.f;
            if (gy >= 0 && gy < H && gx >= 0 && gx < W) {
                const float* p = which ? xRn : xCn;
                v = p[(size_t)(ic0 + ic) * HW + (size_t)gy * W + gx];
            }
            if (which) sInR[ic][ly][lx] = v; else sInC[ic][ly][lx] = v;
        }
        for (int e = tid; e < 88 * 72; e += 256) {
            int o = e / 72;
            int r = e % 72;
            float wv = 0.f;
            if (o < 80)       wv = sw[(size_t)o * 2304 + (size_t)ic0 * 9 + r];
            else if (o == 80) wv = cw[(size_t)ic0 * 9 + r];
            else if (o < 85)  wv = pw[(size_t)(o - 81) * 2304 + (size_t)ic0 * 9 + r];
            sWt[o][r] = wv;
        }
        __syncthreads();

        for (int ic = 0; ic < ICC; ++ic) {
            float winC[9], winR[9];
#pragma unroll
            for (int ky = 0; ky < 3; ++ky)
#pragma unroll
                for (int kx = 0; kx < 3; ++kx) {
                    winC[ky * 3 + kx] = sInC[ic][prow + ky][pcol + kx];
                    winR[ky * 3 + kx] = sInR[ic][prow + ky][pcol + kx];
                }
#pragma unroll
            for (int k = 0; k < 22; ++k) {
                int oc = base + k;
                const float* wr = &sWt[oc][ic * 9];
                float s = 0.f;
                if (oc < 80) {
#pragma unroll
                    for (int t = 0; t < 9; ++t) s += wr[t] * winC[t];
                } else {
#pragma unroll
                    for (int t = 0; t < 9; ++t) s += wr[t] * winR[t];
                }
                acc[k] += s;
            }
        }
    }

    __syncthreads();   // weights dead; reuse LDS as sOut
#pragma unroll
    for (int k = 0; k < 22; ++k) sOut[base + k][pos] = acc[k];
    __syncthreads();

    const float scl = scales[lvl];
    for (int e = tid; e < 64 * 84; e += 256) {
        int p = e / 84;
        int j = e - p * 84;
        int py = ty0 + (p >> 4);
        int px = tx0 + (p & 15);
        if (py < H && px < W) {
            float v;
            if (j < 80) {
                float sc = 1.f / (1.f + __expf(-sOut[80][p]));
                v = sc / (1.f + __expf(-sOut[j][p]));
            } else {
                int d = j - 80;
                float rg = fmaxf(sOut[81 + d][p] * scl, 0.f) * stride;
                float sx = px * stride;
                float sy = py * stride;
                v = (d == 0) ? sx - rg : (d == 1) ? sy - rg
                  : (d == 2) ? sx + rg : sy + rg;
            }
            size_t row = (size_t)row_off + (size_t)py * W + px;
            out[((size_t)n * TOTROW + row) * 84 + j] = v;
        }
    }
}

// ---------------------------------------------------------------------------
extern "C" void kernel_launch(void* const* d_in, const int* in_sizes, int n_in,
                              void* d_out, int out_size, void* d_ws, size_t ws_size,
                              hipStream_t stream)
{
    (void)in_sizes; (void)n_in; (void)out_size; (void)ws_size;

    const float* feats[5];
    for (int l = 0; l < 5; ++l) feats[l] = (const float*)d_in[l];
    const float* cls_w  = (const float*)d_in[5];
    const float* cls_b  = (const float*)d_in[6];
    const float* cls_gw = (const float*)d_in[7];
    const float* cls_gb = (const float*)d_in[8];
    const float* box_w  = (const float*)d_in[9];
    const float* box_b  = (const float*)d_in[10];
    const float* box_gw = (const float*)d_in[11];
    const float* box_gb = (const float*)d_in[12];
    const float* score_w = (const float*)d_in[13];
    const float* score_b = (const float*)d_in[14];
    const float* pred_w  = (const float*)d_in[15];
    const float* pred_b  = (const float*)d_in[16];
    const float* ctr_w   = (const float*)d_in[17];
    const float* ctr_b   = (const float*)d_in[18];
    const float* scales  = (const float*)d_in[19];
    float* out = (float*)d_out;

    float* ws = (float*)d_ws;
    const size_t BUF = (size_t)2 * CCH * 16000;   // max level: 2*256*100*160 floats
    float* Xc = ws;
    float* Yc = ws + BUF;
    float* Xr = ws + 2 * BUF;
    float* Yr = ws + 3 * BUF;
    float* stats = ws + 4 * BUF;

    const size_t WL = (size_t)CCH * CCH * 9;      // per-layer weight stride

    for (int l = 0; l < NLEV; ++l) {
        const int H = Hs[l], W = Ws[l], HW = H * W;
        const int tiles = ((W + TW - 1) / TW) * ((H + TH - 1) / TH);
        for (int i = 0; i < 4; ++i) {
            const float* ic_ = (i == 0) ? feats[l] : Xc;
            const float* ir_ = (i == 0) ? feats[l] : Xr;
            conv_tower<<<dim3(tiles, 4, 4), 256, 0, stream>>>(
                ic_, ir_, Yc, Yr,
                cls_w + (size_t)i * WL, cls_b + i * CCH,
                box_w + (size_t)i * WL, box_b + i * CCH, H, W);
            gn_stats<<<dim3(GRP, 2, 2), 256, 0, stream>>>(Yc, Yr, stats, HW);
            gn_apply<<<dim3((HW + 255) / 256, 2 * CCH, 2), 256, 0, stream>>>(
                Yc, Yr, Xc, Xr, stats,
                cls_gw + i * CCH, cls_gb + i * CCH,
                box_gw + i * CCH, box_gb + i * CCH, HW);
        }
        head_kernel<<<dim3(tiles, 2), 256, 0, stream>>>(
            Xc, Xr, score_w, score_b, ctr_w, ctr_b, pred_w, pred_b,
            scales, l, out, H, W, ROFF[l], (float)STRD[l]);
    }
}

// Round 2
// 2318.013 us; speedup vs baseline: 7.7692x; 7.7692x over previous
//
#include <hip/hip_runtime.h>
#include <cstddef>

#define NLEV 5
#define TOTROW 21330

static const int Hs[NLEV]   = {100, 50, 25, 13, 7};
static const int Ws[NLEV]   = {160, 80, 40, 20, 10};
static const int ROFF[NLEV] = {0, 16000, 20000, 21000, 21260};
static const int STRD[NLEV] = {8, 16, 32, 64, 128};

typedef __bf16 bf16x8 __attribute__((ext_vector_type(8)));
typedef float f32x4 __attribute__((ext_vector_type(4)));
typedef unsigned short ushortx8 __attribute__((ext_vector_type(8)));

static __device__ __forceinline__ unsigned short f2bf(float f) {
  union { float f; unsigned u; } v; v.f = f;
  unsigned r = v.u + 0x7fffu + ((v.u >> 16) & 1u);
  return (unsigned short)(r >> 16);
}
static __device__ __forceinline__ float bf2f(unsigned short h) {
  union { unsigned u; float f; } v; v.u = ((unsigned)h) << 16;
  return v.f;
}

// ---------------------------------------------------------------------------
// NCHW fp32 -> [n][pos][256] bf16 (LDS-tiled transpose)
// grid: (ceil(HW/64), 8)  y: n = y>>2, cb = y&3
// ---------------------------------------------------------------------------
__global__ __launch_bounds__(256) void to_chlast(
    const float* __restrict__ feat, unsigned short* __restrict__ X, int HW)
{
  const int n = blockIdx.y >> 2, cb = blockIdx.y & 3;
  const int p0 = blockIdx.x * 64;
  __shared__ unsigned short s[64][72];
  const int t = threadIdx.x;
  const int pl = t & 63, ci = t >> 6;
  const float* src = feat + ((size_t)(n * 256 + cb * 64)) * HW;
#pragma unroll
  for (int i = 0; i < 16; ++i) {
    const int c = ci + i * 4;
    const int p = p0 + pl;
    float v = (p < HW) ? src[(size_t)c * HW + p] : 0.f;
    s[c][pl] = f2bf(v);
  }
  __syncthreads();
  const int cl = t & 63, pi = t >> 6;
#pragma unroll
  for (int i = 0; i < 16; ++i) {
    const int p = p0 + pi + i * 4;
    if (p < HW) X[((size_t)n * HW + p) * 256 + cb * 64 + cl] = s[cl][pi + i * 4];
  }
}

// ---------------------------------------------------------------------------
// tower weights fp32 [4][256][256][3][3] -> bf16 [layer][tap][oc][ic]
// ---------------------------------------------------------------------------
__global__ __launch_bounds__(256) void prep_tower_w(
    const float* __restrict__ cls_w, const float* __restrict__ box_w,
    unsigned short* __restrict__ wtC, unsigned short* __restrict__ wtR)
{
  const long e = (long)blockIdx.x * 256 + threadIdx.x;
  if (e >= 2359296L) return;
  const int layer = (int)(e / 589824);
  const int r1 = (int)(e % 589824);
  const int tap = r1 >> 16;
  const int r3 = r1 & 65535;
  const int o = r3 >> 8, i = r3 & 255;
  const long src = (((long)layer * 256 + o) * 256 + i) * 9 + tap;
  wtC[e] = f2bf(cls_w[src]);
  wtR[e] = f2bf(box_w[src]);
}

// ---------------------------------------------------------------------------
// head weights -> bf16 [9][128][512]  (k<256: cls input; k>=256: box input)
// oc 0..79 score, 80 ctr, 81..84 pred, rest zero. Also builds bias[128].
// ---------------------------------------------------------------------------
__global__ __launch_bounds__(256) void prep_head_w(
    const float* __restrict__ sw, const float* __restrict__ sb,
    const float* __restrict__ cw, const float* __restrict__ cb,
    const float* __restrict__ pw, const float* __restrict__ pb,
    unsigned short* __restrict__ wth, float* __restrict__ bh)
{
  const long e = (long)blockIdx.x * 256 + threadIdx.x;
  if (e < 589824L) {
    const int tap = (int)(e >> 16);
    const int r = (int)(e & 65535);
    const int oc = r >> 9, k = r & 511;
    float v = 0.f;
    if (oc < 80) { if (k < 256) v = sw[((long)(oc * 256 + k)) * 9 + tap]; }
    else if (oc == 80) { if (k >= 256) v = cw[(long)(k - 256) * 9 + tap]; }
    else if (oc < 85) { if (k >= 256) v = pw[((long)((oc - 81) * 256 + (k - 256))) * 9 + tap]; }
    wth[e] = f2bf(v);
  }
  if (blockIdx.x == 0) {
    const int t = threadIdx.x;
    if (t < 128) bh[t] = (t < 80) ? sb[t] : (t == 80) ? cb[0] : (t < 85) ? pb[t - 81] : 0.f;
  }
}

// ---------------------------------------------------------------------------
// MFMA implicit-GEMM 3x3 conv.  M-tile 256 (16x16 spatial), N-tile 64 oc.
// Activations [img][pos][256] bf16, weights [tap][OCW][KTOT] bf16.
// kimg=1: tower mode, z = tower*2+n, K=256.  kimg=2: head, z = n, K=512
// (first 256 from inC=cls acts, second 256 from inR=box acts).
// stats!=null: accumulate GN partial (sum,sumsq) per (img,group) via atomics.
// ---------------------------------------------------------------------------
__global__ __launch_bounds__(256) void conv_mfma(
    const unsigned short* __restrict__ inC, const unsigned short* __restrict__ inR,
    unsigned short* __restrict__ outC, unsigned short* __restrict__ outR,
    const unsigned short* __restrict__ wtC, const unsigned short* __restrict__ wtR,
    const float* __restrict__ bsC, const float* __restrict__ bsR,
    float* __restrict__ stats,
    int H, int W, int kimg, int octot)
{
  const int HW = H * W;
  const int tilesX = (W + 15) >> 4;
  const int x0 = (blockIdx.x % tilesX) << 4;
  const int y0 = (blockIdx.x / tilesX) << 4;
  const int oc0 = blockIdx.y << 6;
  const int z = blockIdx.z;

  const unsigned short *A0, *A1, *wt;
  const float* bs; unsigned short* out;
  if (kimg == 1) {
    const int tower = z >> 1, n = z & 1;
    const unsigned short* a = (tower ? inR : inC) + (size_t)n * HW * 256;
    A0 = a; A1 = a;
    wt = tower ? wtR : wtC;
    bs = tower ? bsR : bsC;
    out = (tower ? outR : outC) + (size_t)n * HW * octot;
  } else {
    A0 = inC + (size_t)z * HW * 256;
    A1 = inR + (size_t)z * HW * 256;
    wt = wtC; bs = bsC;
    out = outC + (size_t)z * HW * octot;
  }
  const int nchunk = kimg << 3;
  const int KTOT = kimg << 8;

  __shared__ unsigned short sA[324 * 32];     // [halo pos][32 ic], 16B-chunk XOR swizzle
  __shared__ unsigned short sB[9 * 64 * 32];  // [tap][oc][32 ic], XOR swizzle

  const int tid = threadIdx.x;
  const int wv = tid >> 6, lane = tid & 63;
  const int t15 = lane & 15, q = lane >> 4;

  f32x4 acc[4][4];
#pragma unroll
  for (int g = 0; g < 4; ++g) {
    const float b = bs[oc0 + g * 16 + t15];
#pragma unroll
    for (int f = 0; f < 4; ++f) {
      acc[f][g][0] = b; acc[f][g][1] = b; acc[f][g][2] = b; acc[f][g][3] = b;
    }
  }

  for (int ch = 0; ch < nchunk; ++ch) {
    const unsigned short* Ap = (ch < 8) ? A0 : A1;
    const int icb = (ch & 7) << 5;
    __syncthreads();
    // stage A halo: 324 positions x 4 x 16B
    for (int e = tid; e < 1296; e += 256) {
      const int pos = e >> 2, part = e & 3;
      const int hy = pos / 18;
      const int hx = pos - hy * 18;
      const int gy = y0 + hy - 1, gx = x0 + hx - 1;
      uint4 v = make_uint4(0u, 0u, 0u, 0u);
      if ((unsigned)gy < (unsigned)H && (unsigned)gx < (unsigned)W)
        v = *(const uint4*)(Ap + (((size_t)(gy * W + gx)) << 8) + icb + (part << 3));
      *(uint4*)(sA + (pos << 5) + (((part ^ pos) & 3) << 3)) = v;
    }
    // stage B: 9 taps x 64 oc x 4 x 16B
    for (int e = tid; e < 2304; e += 256) {
      const int tap = e >> 8, rr = e & 255;
      const int ocl = rr >> 2, part = rr & 3;
      uint4 v = *(const uint4*)(wt + (size_t)(tap * octot + oc0 + ocl) * KTOT + (ch << 5) + (part << 3));
      *(uint4*)(sB + ((tap * 64 + ocl) << 5) + (((part ^ ocl) & 3) << 3)) = v;
    }
    __syncthreads();

#pragma unroll
    for (int ky = 0; ky < 3; ++ky) {
#pragma unroll
      for (int kx = 0; kx < 3; ++kx) {
        const int tap = ky * 3 + kx;
        bf16x8 a[4], b[4];
#pragma unroll
        for (int f = 0; f < 4; ++f) {
          const int pos = (wv * 4 + f + ky) * 18 + t15 + kx;
          a[f] = *(const bf16x8*)(sA + (pos << 5) + (((q ^ pos) & 3) << 3));
        }
#pragma unroll
        for (int g = 0; g < 4; ++g) {
          const int ocl = g * 16 + t15;
          b[g] = *(const bf16x8*)(sB + ((tap * 64 + ocl) << 5) + (((q ^ ocl) & 3) << 3));
        }
#pragma unroll
        for (int f = 0; f < 4; ++f)
#pragma unroll
          for (int g = 0; g < 4; ++g)
            acc[f][g] = __builtin_amdgcn_mfma_f32_16x16x32_bf16(a[f], b[g], acc[f][g], 0, 0, 0);
      }
    }
  }

  // epilogue: store bf16 + fused GN partial stats
#pragma unroll
  for (int g = 0; g < 4; ++g) {
    const int oc = oc0 + g * 16 + t15;
    float s = 0.f, ss = 0.f;
#pragma unroll
    for (int f = 0; f < 4; ++f) {
      const int gy = y0 + wv * 4 + f;
#pragma unroll
      for (int rg = 0; rg < 4; ++rg) {
        const int gx = x0 + q * 4 + rg;
        if (gy < H && gx < W) {
          const float v = acc[f][g][rg];
          out[(size_t)(gy * W + gx) * octot + oc] = f2bf(v);
          s += v; ss += v * v;
        }
      }
    }
    if (stats) {
      s += __shfl_xor(s, 1);  ss += __shfl_xor(ss, 1);
      s += __shfl_xor(s, 2);  ss += __shfl_xor(ss, 2);
      s += __shfl_xor(s, 4);  ss += __shfl_xor(ss, 4);
      s += __shfl_xor(s, 16); ss += __shfl_xor(ss, 16);
      s += __shfl_xor(s, 32); ss += __shfl_xor(ss, 32);
      if ((lane & 55) == 0) {   // lanes 0 and 8: groups (oc>>3) for t15<8 / >=8
        float* st = stats + ((size_t)z * 32 + (oc >> 3)) * 2;
        atomicAdd(st, s); atomicAdd(st + 1, ss);
      }
    }
  }
}

// ---------------------------------------------------------------------------
// GN apply + ReLU on bf16 channel-last. grid: (ceil(HW*32/256), 4 imgs)
// ---------------------------------------------------------------------------
__global__ __launch_bounds__(256) void gn_apply(
    const unsigned short* __restrict__ Yc, const unsigned short* __restrict__ Yr,
    unsigned short* __restrict__ Xc, unsigned short* __restrict__ Xr,
    const float* __restrict__ stats,
    const float* __restrict__ gwC, const float* __restrict__ gbC,
    const float* __restrict__ gwR, const float* __restrict__ gbR,
    int HW)
{
  const int img = blockIdx.y;
  const int tower = img >> 1, n = img & 1;
  const int e = blockIdx.x * 256 + threadIdx.x;
  const int g = e & 31;
  const int pos = e >> 5;
  if (pos >= HW) return;
  const size_t off = ((size_t)n * HW + pos) * 256 + g * 8;
  const unsigned short* Y = (tower ? Yr : Yc) + off;
  unsigned short* X = (tower ? Xr : Xc) + off;
  const float* gw = (tower ? gwR : gwC) + g * 8;
  const float* gb = (tower ? gbR : gbC) + g * 8;
  const float* st = stats + ((size_t)img * 32 + g) * 2;
  const float inv = 1.f / (8.f * (float)HW);
  const float m = st[0] * inv;
  const float var = st[1] * inv - m * m;
  const float rs = rsqrtf(var + 1e-5f);
  ushortx8 yv = *(const ushortx8*)Y;
  ushortx8 xv;
#pragma unroll
  for (int j = 0; j < 8; ++j) {
    const float y = bf2f(yv[j]);
    const float v = (y - m) * rs * gw[j] + gb[j];
    xv[j] = f2bf(fmaxf(v, 0.f));
  }
  *(ushortx8*)X = xv;
}

// ---------------------------------------------------------------------------
// Head epilogue: Yh [n][HW][128] bf16 -> out [n][row][84] fp32
// ---------------------------------------------------------------------------
__global__ __launch_bounds__(256) void head_epi(
    const unsigned short* __restrict__ Yh, float* __restrict__ out,
    const float* __restrict__ scales, int lvl, int H, int W, int roff, float stride)
{
  const int n = blockIdx.y;
  const int HW = H * W;
  const int e = blockIdx.x * 256 + threadIdx.x;
  if (e >= HW * 84) return;
  const int pos = e / 84;
  const int j = e - pos * 84;
  const unsigned short* yp = Yh + ((size_t)n * HW + pos) * 128;
  float v;
  if (j < 80) {
    const float lg = bf2f(yp[j]);
    const float ct = bf2f(yp[80]);
    v = (1.f / (1.f + __expf(-lg))) * (1.f / (1.f + __expf(-ct)));
  } else {
    const int d = j - 80;
    const float pv = bf2f(yp[81 + d]);
    const float rg = fmaxf(pv * scales[lvl], 0.f) * stride;
    const int gy = pos / W, gx = pos - gy * W;
    const float sx = gx * stride, sy = gy * stride;
    v = (d == 0) ? sx - rg : (d == 1) ? sy - rg : (d == 2) ? sx + rg : sy + rg;
  }
  out[((size_t)n * TOTROW + roff + pos) * 84 + j] = v;
}

// ---------------------------------------------------------------------------
extern "C" void kernel_launch(void* const* d_in, const int* in_sizes, int n_in,
                              void* d_out, int out_size, void* d_ws, size_t ws_size,
                              hipStream_t stream)
{
  (void)in_sizes; (void)n_in; (void)out_size; (void)ws_size;

  const float* feats[5];
  for (int l = 0; l < 5; ++l) feats[l] = (const float*)d_in[l];
  const float* cls_w  = (const float*)d_in[5];
  const float* cls_b  = (const float*)d_in[6];
  const float* cls_gw = (const float*)d_in[7];
  const float* cls_gb = (const float*)d_in[8];
  const float* box_w  = (const float*)d_in[9];
  const float* box_b  = (const float*)d_in[10];
  const float* box_gw = (const float*)d_in[11];
  const float* box_gb = (const float*)d_in[12];
  const float* score_w = (const float*)d_in[13];
  const float* score_b = (const float*)d_in[14];
  const float* pred_w  = (const float*)d_in[15];
  const float* pred_b  = (const float*)d_in[16];
  const float* ctr_w   = (const float*)d_in[17];
  const float* ctr_b   = (const float*)d_in[18];
  const float* scales  = (const float*)d_in[19];
  float* out = (float*)d_out;

  char* p = (char*)d_ws;
  auto alloc = [&](size_t bytes) {
    char* r = p;
    p += (bytes + 255) & ~(size_t)255;
    return r;
  };
  unsigned short* Xf  = (unsigned short*)alloc(16384000);  // [n][HW][256] level input
  unsigned short* Xc  = (unsigned short*)alloc(16384000);
  unsigned short* Xr  = (unsigned short*)alloc(16384000);
  unsigned short* Yc  = (unsigned short*)alloc(16384000);
  unsigned short* Yr  = (unsigned short*)alloc(16384000);
  unsigned short* Yh  = (unsigned short*)alloc(8192000);   // [n][HW][128]
  unsigned short* wtC = (unsigned short*)alloc(4718592);   // [4][9][256][256] bf16
  unsigned short* wtR = (unsigned short*)alloc(4718592);
  unsigned short* wth = (unsigned short*)alloc(1179648);   // [9][128][512] bf16
  float* bh    = (float*)alloc(512);
  float* stats = (float*)alloc(20 * 256 * sizeof(float));  // [5 lvl][4 layer][4 img][32 g][2]

  hipMemsetAsync(stats, 0, 20 * 256 * sizeof(float), stream);
  prep_tower_w<<<(2359296 + 255) / 256, 256, 0, stream>>>(cls_w, box_w, wtC, wtR);
  prep_head_w<<<(589824 + 255) / 256, 256, 0, stream>>>(score_w, score_b, ctr_w, ctr_b,
                                                        pred_w, pred_b, wth, bh);

  for (int l = 0; l < NLEV; ++l) {
    const int H = Hs[l], W = Ws[l], HW = H * W;
    const int tiles = ((W + 15) / 16) * ((H + 15) / 16);

    to_chlast<<<dim3((HW + 63) / 64, 8), 256, 0, stream>>>(feats[l], Xf, HW);

    for (int i = 0; i < 4; ++i) {
      const unsigned short* ic_ = (i == 0) ? Xf : Xc;
      const unsigned short* ir_ = (i == 0) ? Xf : Xr;
      float* st = stats + (size_t)(l * 4 + i) * 256;
      conv_mfma<<<dim3(tiles, 4, 4), 256, 0, stream>>>(
          ic_, ir_, Yc, Yr,
          wtC + (size_t)i * 589824, wtR + (size_t)i * 589824,
          cls_b + i * 256, box_b + i * 256,
          st, H, W, 1, 256);
      gn_apply<<<dim3((HW * 32 + 255) / 256, 4), 256, 0, stream>>>(
          Yc, Yr, Xc, Xr, st,
          cls_gw + i * 256, cls_gb + i * 256,
          box_gw + i * 256, box_gb + i * 256, HW);
    }

    conv_mfma<<<dim3(tiles, 2, 2), 256, 0, stream>>>(
        Xc, Xr, Yh, nullptr, wth, nullptr, bh, nullptr, nullptr, H, W, 2, 128);
    head_epi<<<dim3((HW * 84 + 255) / 256, 2), 256, 0, stream>>>(
        Yh, out, scales, l, H, W, ROFF[l], (float)STRD[l]);
  }
}

// Round 3
// 1135.731 us; speedup vs baseline: 15.8569x; 2.0410x over previous
//
#include <hip/hip_runtime.h>
#include <cstddef>

#define NLEV 5
#define TOTROW 21330
#define PTOT 22360   // sum of (H+2)*(W+2)

typedef __bf16 bf16x8 __attribute__((ext_vector_type(8)));
typedef float f32x4 __attribute__((ext_vector_type(4)));
typedef unsigned short ushortx8 __attribute__((ext_vector_type(8)));

struct LvlP {
  int tileoff[6];
  int tilesX[5];
  int H[5], W[5];
  int poff[5], pend[5];
  int roff[6];
  float inv8HW[5];
  float strd[5];
};

static __device__ __forceinline__ unsigned short f2bf(float f) {
  union { float f; unsigned u; } v; v.f = f;
  unsigned r = v.u + 0x7fffu + ((v.u >> 16) & 1u);
  return (unsigned short)(r >> 16);
}
static __device__ __forceinline__ float bf2f(unsigned short h) {
  union { unsigned u; float f; } v; v.u = ((unsigned)h) << 16;
  return v.f;
}
static __device__ __forceinline__ int sel5i(const int* a, int l) {
  int v = a[0];
  v = (l == 1) ? a[1] : v; v = (l == 2) ? a[2] : v;
  v = (l == 3) ? a[3] : v; v = (l == 4) ? a[4] : v;
  return v;
}
static __device__ __forceinline__ float sel5f(const float* a, int l) {
  float v = a[0];
  v = (l == 1) ? a[1] : v; v = (l == 2) ? a[2] : v;
  v = (l == 3) ? a[3] : v; v = (l == 4) ? a[4] : v;
  return v;
}

static __device__ __forceinline__ void gload16(const unsigned short* g, unsigned short* l) {
  __builtin_amdgcn_global_load_lds(
      (const __attribute__((address_space(1))) unsigned int*)(const void*)g,
      (__attribute__((address_space(3))) unsigned int*)(void*)l, 16, 0, 0);
}

// ---------------------------------------------------------------------------
// NCHW fp32 -> padded channel-last bf16: X[n][poff + (y+1)*(W+2)+(x+1)][256]
// ---------------------------------------------------------------------------
__global__ __launch_bounds__(256) void to_chlast(
    const float* __restrict__ feat, unsigned short* __restrict__ X,
    int HW, int W, int poff)
{
  const int n = blockIdx.y >> 2, cb = blockIdx.y & 3;
  const int p0 = blockIdx.x * 64;
  __shared__ unsigned short s[64][72];
  const int t = threadIdx.x;
  const int pl = t & 63, ci = t >> 6;
  const float* src = feat + ((size_t)(n * 256 + cb * 64)) * HW;
#pragma unroll
  for (int i = 0; i < 16; ++i) {
    const int c = ci + i * 4;
    const int p = p0 + pl;
    float v = (p < HW) ? src[(size_t)c * HW + p] : 0.f;
    s[c][pl] = f2bf(v);
  }
  __syncthreads();
  const int cl = t & 63, pi = t >> 6;
#pragma unroll
  for (int i = 0; i < 16; ++i) {
    const int p = p0 + pi + i * 4;
    if (p < HW) {
      const int y = p / W, x = p - y * W;
      const size_t dst = ((size_t)n * PTOT + poff + (y + 1) * (W + 2) + (x + 1)) * 256
                       + cb * 64 + cl;
      X[dst] = s[cl][pi + i * 4];
    }
  }
}

// ---------------------------------------------------------------------------
// tower weights fp32 [4][256][256][3][3] -> bf16 [layer][ch8][tap9][q4][oc256][8]
// ---------------------------------------------------------------------------
__global__ __launch_bounds__(256) void prep_tower_w(
    const float* __restrict__ cls_w, const float* __restrict__ box_w,
    unsigned short* __restrict__ wtC, unsigned short* __restrict__ wtR)
{
  const long e = (long)blockIdx.x * 256 + threadIdx.x;
  if (e >= 2359296L) return;
  const int j = (int)(e & 7);
  long r = e >> 3;
  const int oc = (int)(r & 255); r >>= 8;
  const int q = (int)(r & 3); r >>= 2;
  const int tap = (int)(r % 9);
  const long s = r / 9;
  const int ch = (int)(s & 7);
  const int layer = (int)(s >> 3);
  const int ic = ch * 32 + q * 8 + j;
  const long src = (((long)layer * 256 + oc) * 256 + ic) * 9 + tap;
  wtC[e] = f2bf(cls_w[src]);
  wtR[e] = f2bf(box_w[src]);
}

// ---------------------------------------------------------------------------
// head weights -> bf16 [ch16][tap9][q4][oc128][8]; k = ch*32+q*8+j in [0,512)
// k<256: cls-tower input (score); k>=256: box-tower input (ctr/pred)
// ---------------------------------------------------------------------------
__global__ __launch_bounds__(256) void prep_head_w(
    const float* __restrict__ sw, const float* __restrict__ sb,
    const float* __restrict__ cw, const float* __restrict__ cb,
    const float* __restrict__ pw, const float* __restrict__ pb,
    unsigned short* __restrict__ wth, float* __restrict__ bh)
{
  const long e = (long)blockIdx.x * 256 + threadIdx.x;
  if (e < 589824L) {
    const int j = (int)(e & 7);
    long r = e >> 3;
    const int oc = (int)(r & 127); r >>= 7;
    const int q = (int)(r & 3); r >>= 2;
    const int tap = (int)(r % 9);
    const int ch = (int)(r / 9);
    const int k = ch * 32 + q * 8 + j;
    float v = 0.f;
    if (oc < 80) { if (k < 256) v = sw[((long)(oc * 256 + k)) * 9 + tap]; }
    else if (oc == 80) { if (k >= 256) v = cw[(long)(k - 256) * 9 + tap]; }
    else if (oc < 85) { if (k >= 256) v = pw[((long)((oc - 81) * 256 + (k - 256))) * 9 + tap]; }
    wth[e] = f2bf(v);
  }
  if (blockIdx.x == 0) {
    const int t = threadIdx.x;
    if (t < 128) bh[t] = (t < 80) ? sb[t] : (t == 80) ? cb[0] : (t < 85) ? pb[t - 81] : 0.f;
  }
}

// ---------------------------------------------------------------------------
// MFMA implicit-GEMM 3x3 conv, all levels in one dispatch.
// Tile M=192 (16x x 12y), N=64 oc. Async global_load_lds staging (16B).
// kimg=1: towers, z=tower*2+n, K=256. kimg=2: head, z=n, K=512 (cls||box).
// Input activations padded [img][PTOT][256]; output unpadded [img][TOTROW][oct].
// ---------------------------------------------------------------------------
__global__ __launch_bounds__(256, 3) void conv_mfma(
    const unsigned short* __restrict__ inC, const unsigned short* __restrict__ inR,
    unsigned short* __restrict__ outC, unsigned short* __restrict__ outR,
    const unsigned short* __restrict__ wtC, const unsigned short* __restrict__ wtR,
    const float* __restrict__ bsC, const float* __restrict__ bsR,
    float* __restrict__ stats, LvlP P, int kimg, int octot)
{
  const int bt = blockIdx.x;
  const int l = (bt >= P.tileoff[1]) + (bt >= P.tileoff[2])
              + (bt >= P.tileoff[3]) + (bt >= P.tileoff[4]);
  const int t = bt - sel5i(P.tileoff, l);
  const int tX = sel5i(P.tilesX, l);
  const int ty = t / tX, tx = t - ty * tX;
  const int x0 = tx << 4, y0 = ty * 12;
  const int H = sel5i(P.H, l), W = sel5i(P.W, l);
  const int W2 = W + 2;
  const int pbase = sel5i(P.poff, l);
  const int pmax = sel5i(P.pend, l) - 1;
  const int rbase = sel5i(P.roff, l);
  const int oc0 = blockIdx.y << 6;
  const int z = blockIdx.z;

  const unsigned short *A0, *A1, *wt;
  const float* bs; unsigned short* out;
  if (kimg == 1) {
    const int tower = z >> 1, n = z & 1;
    const unsigned short* a = (tower ? inR : inC) + (size_t)n * PTOT * 256;
    A0 = a; A1 = a;
    wt = tower ? wtR : wtC;
    bs = tower ? bsR : bsC;
    out = (tower ? outR : outC) + (size_t)n * TOTROW * octot;
  } else {
    A0 = inC + (size_t)z * PTOT * 256;
    A1 = inR + (size_t)z * PTOT * 256;
    wt = wtC; bs = bsC;
    out = outC + (size_t)z * TOTROW * octot;
  }
  const int nchunk = kimg << 3;

  __shared__ unsigned short sA[16 * 512];   // [pos 252(+pad)][part4][8ic] 16 KB
  __shared__ unsigned short sB[36 * 512];   // [tap][q][oc64][8ic]         36 KB

  const int tid = threadIdx.x;
  const int wv = tid >> 6, lane = tid & 63;
  const int t15 = lane & 15, q = lane >> 4;

  f32x4 acc[3][4];
#pragma unroll
  for (int g = 0; g < 4; ++g) {
    const float b = bs[oc0 + g * 16 + t15];
#pragma unroll
    for (int f = 0; f < 3; ++f) {
      acc[f][g][0] = b; acc[f][g][1] = b; acc[f][g][2] = b; acc[f][g][3] = b;
    }
  }

  for (int ch = 0; ch < nchunk; ++ch) {
    const unsigned short* Ap = (ch < 8) ? A0 : A1;
    const int icb = (ch & 7) << 5;
    __syncthreads();
    // A stage: 16 wave-instructions of 64 lanes x 16 B (linear LDS)
#pragma unroll
    for (int it = 0; it < 4; ++it) {
      const int inst = wv + it * 4;
      const int item = (inst << 6) + lane;
      int pos = item >> 2; pos = (pos > 251) ? 251 : pos;
      const int part = item & 3;
      const int hy = pos / 18, hx = pos - hy * 18;
      int pidx = pbase + (y0 + hy) * W2 + (x0 + hx);
      pidx = (pidx > pmax) ? pmax : pidx;
      gload16(Ap + (((size_t)pidx) << 8) + icb + (part << 3), sA + (inst << 9));
    }
    // B stage: 36 wave-instructions, fully contiguous 1 KB each
    const unsigned short* wb = wt + ((size_t)(ch * 36) * octot + oc0) * 8 + (lane << 3);
#pragma unroll
    for (int it = 0; it < 9; ++it) {
      const int inst = wv + it * 4;
      gload16(wb + (size_t)inst * octot * 8, sB + (inst << 9));
    }
    __syncthreads();

#pragma unroll
    for (int ky = 0; ky < 3; ++ky) {
#pragma unroll
      for (int kx = 0; kx < 3; ++kx) {
        const int tap = ky * 3 + kx;
        bf16x8 a[3], b[4];
#pragma unroll
        for (int f = 0; f < 3; ++f) {
          const int pos = (wv * 3 + f + ky) * 18 + t15 + kx;
          a[f] = *(const bf16x8*)(sA + ((pos * 4 + q) << 3));
        }
#pragma unroll
        for (int g = 0; g < 4; ++g)
          b[g] = *(const bf16x8*)(sB + ((((tap * 4 + q) << 6) + g * 16 + t15) << 3));
#pragma unroll
        for (int f = 0; f < 3; ++f)
#pragma unroll
          for (int g = 0; g < 4; ++g)
            acc[f][g] = __builtin_amdgcn_mfma_f32_16x16x32_bf16(a[f], b[g], acc[f][g], 0, 0, 0);
      }
    }
  }

  // epilogue: store bf16 + fused GN partial stats
#pragma unroll
  for (int g = 0; g < 4; ++g) {
    const int oc = oc0 + g * 16 + t15;
    float s = 0.f, ss = 0.f;
#pragma unroll
    for (int f = 0; f < 3; ++f) {
      const int gy = y0 + wv * 3 + f;
#pragma unroll
      for (int rg = 0; rg < 4; ++rg) {
        const int gx = x0 + q * 4 + rg;
        if (gy < H && gx < W) {
          const float v = acc[f][g][rg];
          out[(size_t)(rbase + gy * W + gx) * octot + oc] = f2bf(v);
          s += v; ss += v * v;
        }
      }
    }
    if (stats) {
      s += __shfl_xor(s, 1);  ss += __shfl_xor(ss, 1);
      s += __shfl_xor(s, 2);  ss += __shfl_xor(ss, 2);
      s += __shfl_xor(s, 4);  ss += __shfl_xor(ss, 4);
      s += __shfl_xor(s, 16); ss += __shfl_xor(ss, 16);
      s += __shfl_xor(s, 32); ss += __shfl_xor(ss, 32);
      if ((lane & 55) == 0) {   // lanes 0 and 8 hold the two GN groups of this g
        float* st = stats + (((size_t)l * 4 + z) * 32 + (oc >> 3)) * 2;
        atomicAdd(st, s); atomicAdd(st + 1, ss);
      }
    }
  }
}

// ---------------------------------------------------------------------------
// GN apply + ReLU, merged levels: reads unpadded Y, writes padded X interior.
// grid: (ceil(21330*32/256), 4 imgs)
// ---------------------------------------------------------------------------
__global__ __launch_bounds__(256) void gn_apply(
    const unsigned short* __restrict__ Yc, const unsigned short* __restrict__ Yr,
    unsigned short* __restrict__ Xc, unsigned short* __restrict__ Xr,
    const float* __restrict__ stats,
    const float* __restrict__ gwC, const float* __restrict__ gbC,
    const float* __restrict__ gwR, const float* __restrict__ gbR, LvlP P)
{
  const int img = blockIdx.y;
  const int tower = img >> 1, n = img & 1;
  const int e = blockIdx.x * 256 + threadIdx.x;
  const int pos = e >> 5;
  const int g = e & 31;
  if (pos >= TOTROW) return;
  const int l = (pos >= P.roff[1]) + (pos >= P.roff[2]) + (pos >= P.roff[3]) + (pos >= P.roff[4]);
  const int W = sel5i(P.W, l);
  const int local = pos - sel5i(P.roff, l);
  const int y = local / W, x = local - y * W;
  const size_t dst = ((size_t)n * PTOT + sel5i(P.poff, l) + (y + 1) * (W + 2) + (x + 1)) * 256 + g * 8;
  const size_t srco = ((size_t)n * TOTROW + pos) * 256 + g * 8;
  const unsigned short* Y = (tower ? Yr : Yc) + srco;
  unsigned short* X = (tower ? Xr : Xc) + dst;
  const float* gw = (tower ? gwR : gwC) + g * 8;
  const float* gb = (tower ? gbR : gbC) + g * 8;
  const float* st = stats + (((size_t)l * 4 + img) * 32 + g) * 2;
  const float inv = sel5f(P.inv8HW, l);
  const float m = st[0] * inv;
  const float var = st[1] * inv - m * m;
  const float rs = rsqrtf(var + 1e-5f);
  ushortx8 yv = *(const ushortx8*)Y;
  ushortx8 xv;
#pragma unroll
  for (int j = 0; j < 8; ++j) {
    const float yj = bf2f(yv[j]);
    const float v = (yj - m) * rs * gw[j] + gb[j];
    xv[j] = f2bf(fmaxf(v, 0.f));
  }
  *(ushortx8*)X = xv;
}

// ---------------------------------------------------------------------------
// Head epilogue, merged levels: Yh [n][21330][128] bf16 -> out [n][21330][84]
// ---------------------------------------------------------------------------
__global__ __launch_bounds__(256) void head_epi(
    const unsigned short* __restrict__ Yh, float* __restrict__ out,
    const float* __restrict__ scales, LvlP P)
{
  const int n = blockIdx.y;
  const int e = blockIdx.x * 256 + threadIdx.x;
  if (e >= TOTROW * 84) return;
  const int pos = e / 84;
  const int j = e - pos * 84;
  const int l = (pos >= P.roff[1]) + (pos >= P.roff[2]) + (pos >= P.roff[3]) + (pos >= P.roff[4]);
  const unsigned short* yp = Yh + ((size_t)n * TOTROW + pos) * 128;
  float v;
  if (j < 80) {
    const float lg = bf2f(yp[j]);
    const float ct = bf2f(yp[80]);
    v = (1.f / (1.f + __expf(-lg))) * (1.f / (1.f + __expf(-ct)));
  } else {
    const int d = j - 80;
    const float stride = sel5f(P.strd, l);
    const int W = sel5i(P.W, l);
    const int local = pos - sel5i(P.roff, l);
    const int gy = local / W, gx = local - gy * W;
    const float pv = bf2f(yp[81 + d]);
    const float rg = fmaxf(pv * scales[l], 0.f) * stride;
    const float sx = gx * stride, sy = gy * stride;
    v = (d == 0) ? sx - rg : (d == 1) ? sy - rg : (d == 2) ? sx + rg : sy + rg;
  }
  out[((size_t)n * TOTROW + pos) * 84 + j] = v;
}

// ---------------------------------------------------------------------------
extern "C" void kernel_launch(void* const* d_in, const int* in_sizes, int n_in,
                              void* d_out, int out_size, void* d_ws, size_t ws_size,
                              hipStream_t stream)
{
  (void)in_sizes; (void)n_in; (void)out_size; (void)ws_size;

  const float* feats[5];
  for (int l = 0; l < 5; ++l) feats[l] = (const float*)d_in[l];
  const float* cls_w  = (const float*)d_in[5];
  const float* cls_b  = (const float*)d_in[6];
  const float* cls_gw = (const float*)d_in[7];
  const float* cls_gb = (const float*)d_in[8];
  const float* box_w  = (const float*)d_in[9];
  const float* box_b  = (const float*)d_in[10];
  const float* box_gw = (const float*)d_in[11];
  const float* box_gb = (const float*)d_in[12];
  const float* score_w = (const float*)d_in[13];
  const float* score_b = (const float*)d_in[14];
  const float* pred_w  = (const float*)d_in[15];
  const float* pred_b  = (const float*)d_in[16];
  const float* ctr_w   = (const float*)d_in[17];
  const float* ctr_b   = (const float*)d_in[18];
  const float* scales  = (const float*)d_in[19];
  float* out = (float*)d_out;

  static const int Hs[5] = {100, 50, 25, 13, 7};
  static const int Ws[5] = {160, 80, 40, 20, 10};
  LvlP P;
  { // fill params
    static const int to[6] = {0, 90, 115, 124, 128, 129};
    static const int tX[5] = {10, 5, 3, 2, 1};
    static const int po[5] = {0, 16524, 20788, 21922, 22252};
    static const int pe[5] = {16524, 20788, 21922, 22252, 22360};
    static const int ro[6] = {0, 16000, 20000, 21000, 21260, 21330};
    for (int i = 0; i < 6; ++i) { P.tileoff[i] = to[i]; P.roff[i] = ro[i]; }
    for (int i = 0; i < 5; ++i) {
      P.tilesX[i] = tX[i]; P.H[i] = Hs[i]; P.W[i] = Ws[i];
      P.poff[i] = po[i]; P.pend[i] = pe[i];
      P.inv8HW[i] = 1.f / (8.f * Hs[i] * Ws[i]);
      P.strd[i] = (float)(8 << i);
    }
  }

  char* p = (char*)d_ws;
  auto alloc = [&](size_t bytes) {
    char* r = p;
    p += (bytes + 255) & ~(size_t)255;
    return r;
  };
  const size_t XPAD = (size_t)2 * PTOT * 256 * 2;     // 22.9 MB padded chl-last
  const size_t YSZ  = (size_t)2 * TOTROW * 256 * 2;   // 21.8 MB
  unsigned short* Xf  = (unsigned short*)alloc(XPAD);
  unsigned short* Xc  = (unsigned short*)alloc(XPAD);
  unsigned short* Xr  = (unsigned short*)alloc(XPAD);
  unsigned short* Yc  = (unsigned short*)alloc(YSZ);
  unsigned short* Yr  = (unsigned short*)alloc(YSZ);
  unsigned short* Yh  = (unsigned short*)alloc((size_t)2 * TOTROW * 128 * 2);
  unsigned short* wtC = (unsigned short*)alloc(4718592);
  unsigned short* wtR = (unsigned short*)alloc(4718592);
  unsigned short* wth = (unsigned short*)alloc(1179648);
  float* bh    = (float*)alloc(512);
  float* stats = (float*)alloc(4 * 5 * 4 * 32 * 2 * sizeof(float)); // [layer][lvl][img][g][2]

  hipMemsetAsync(Xf, 0, XPAD, stream);
  hipMemsetAsync(Xc, 0, XPAD, stream);
  hipMemsetAsync(Xr, 0, XPAD, stream);
  hipMemsetAsync(stats, 0, 4 * 5 * 4 * 32 * 2 * sizeof(float), stream);

  prep_tower_w<<<9216, 256, 0, stream>>>(cls_w, box_w, wtC, wtR);
  prep_head_w<<<2304, 256, 0, stream>>>(score_w, score_b, ctr_w, ctr_b,
                                        pred_w, pred_b, wth, bh);
  for (int l = 0; l < 5; ++l) {
    const int HW = Hs[l] * Ws[l];
    to_chlast<<<dim3((HW + 63) / 64, 8), 256, 0, stream>>>(
        feats[l], Xf, HW, Ws[l], P.poff[l]);
  }

  for (int i = 0; i < 4; ++i) {
    const unsigned short* ic_ = (i == 0) ? Xf : Xc;
    const unsigned short* ir_ = (i == 0) ? Xf : Xr;
    float* st = stats + (size_t)i * 5 * 4 * 32 * 2;
    conv_mfma<<<dim3(129, 4, 4), 256, 0, stream>>>(
        ic_, ir_, Yc, Yr,
        wtC + (size_t)i * 589824, wtR + (size_t)i * 589824,
        cls_b + i * 256, box_b + i * 256, st, P, 1, 256);
    gn_apply<<<dim3((TOTROW * 32 + 255) / 256, 4), 256, 0, stream>>>(
        Yc, Yr, Xc, Xr, st,
        cls_gw + i * 256, cls_gb + i * 256,
        box_gw + i * 256, box_gb + i * 256, P);
  }

  conv_mfma<<<dim3(129, 2, 2), 256, 0, stream>>>(
      Xc, Xr, Yh, nullptr, wth, nullptr, bh, nullptr, nullptr, P, 2, 128);
  head_epi<<<dim3((TOTROW * 84 + 255) / 256, 2), 256, 0, stream>>>(
      Yh, out, scales, P);
}